// Round 16
// baseline (158.532 us; speedup 1.0000x reference)
//
#include <hip/hip_runtime.h>
#include <math.h>

// Problem constants: x(256,8192) b,q,e(8192) M(100,8192) out(256,100)
#define NN 8192
#define BB 256
#define CC 100
#define MAX_ITERS 4096
#define T0CAP 384      // phase-A iteration cap (multiple of 4)
#define LISTMAX 4096   // straggler list capacity
#define CHUNK 10       // classes per logits block

__global__ void zero_kernel(unsigned* __restrict__ cnt) { *cnt = 0u; }

// ---------------------------------------------------------------------------
// Fire phase A: r15's exact wave-per-column body, capped at T0CAP iters.
// Finished waves (all-fired or cycle-fast-forward) write k. Unfinished waves
// write NOTHING and append (col<<2)|wavegroup to the straggler list; if the
// list is full (shouldn't happen), they continue inline to MAX_ITERS.
// Locked reference flavor (r10): hoisted IEEE f32 reciprocals; separate
// sub/mul/select; lo=x-e, hi=x+e exact f32 subs. Brent fast-forward credit
// kk += MAX_ITERS - it is exact (survivors of a closed cycle never fire).
// ---------------------------------------------------------------------------
__global__ __launch_bounds__(256) void fireA_kernel(
    const float* __restrict__ x, const float* __restrict__ bmap,
    const float* __restrict__ qini, const float* __restrict__ eps,
    float* __restrict__ kout, unsigned* __restrict__ cnt,
    unsigned* __restrict__ list)
{
    const int j    = blockIdx.x;
    const int lane = threadIdx.x & 63;
    const int wg   = threadIdx.x >> 6;
    const int row  = wg * 64 + lane;

    const float bv  = bmap[j];
    const float qv  = qini[j];
    const float ev  = eps[j];
    const float obv = 1.0f - bv;
    const float rb  = 1.0f / bv;
    const float rob = 1.0f / obv;

    const float xv  = x[(size_t)row * NN + j];
    const float lov = xv - ev;
    const float hiv = xv + ev;

    float m = qv, anchor = qv;
    int   window = 1, steps = 0;
    int   kk = 1;
    bool  a  = (qv != 0.0f);
    bool  cycseen = false;
    bool  finished = false;

    int it = 0;
    while (it < T0CAP) {
        #pragma unroll
        for (int u = 0; u < 4; ++u) {
            const bool  lt = (m < bv);
            const float pa = m * rb;
            const float pb = (1.0f - m) * rob;
            m = lt ? pa : pb;
            cycseen = cycseen || (m == anchor);
            if (++steps == window) { anchor = m; window <<= 1; steps = 0; }
            const bool o = (m < lov) || (m > hiv);
            a = a && o;
            kk += a ? 1 : 0;
        }
        it += 4;
        if (__ballot(a) == 0ull) { finished = true; break; }
        if (cycseen) { kk += a ? (MAX_ITERS - it) : 0; finished = true; break; }
    }

    if (!finished) {
        unsigned idx = 0;
        if (lane == 0) idx = atomicAdd(cnt, 1u);
        idx = (unsigned)__shfl((int)idx, 0, 64);
        if (idx < LISTMAX) {
            if (lane == 0) list[idx] = ((unsigned)j << 2) | (unsigned)wg;
            return;                      // phase B recomputes this wave fully
        }
        // overflow fallback: continue inline to MAX_ITERS (same body)
        while (it < MAX_ITERS) {
            #pragma unroll
            for (int u = 0; u < 4; ++u) {
                const bool  lt = (m < bv);
                const float pa = m * rb;
                const float pb = (1.0f - m) * rob;
                m = lt ? pa : pb;
                cycseen = cycseen || (m == anchor);
                if (++steps == window) { anchor = m; window <<= 1; steps = 0; }
                const bool o = (m < lov) || (m > hiv);
                a = a && o;
                kk += a ? 1 : 0;
            }
            it += 4;
            if (__ballot(a) == 0ull) break;
            if (cycseen) { kk += a ? (MAX_ITERS - it) : 0; break; }
        }
    }

    kout[(size_t)row * NN + j] = (float)kk;
}

// ---------------------------------------------------------------------------
// Fire phase B: rerun straggler waves from scratch (full loop, identical
// body -> bit-exact). One wave per block (64 threads), strided over list.
// ---------------------------------------------------------------------------
__global__ __launch_bounds__(64) void fireB_kernel(
    const float* __restrict__ x, const float* __restrict__ bmap,
    const float* __restrict__ qini, const float* __restrict__ eps,
    float* __restrict__ kout, const unsigned* __restrict__ cnt,
    const unsigned* __restrict__ list)
{
    const unsigned n = min(*cnt, (unsigned)LISTMAX);
    const int lane = threadIdx.x;

    for (unsigned idx = blockIdx.x; idx < n; idx += gridDim.x) {
        const unsigned ent = list[idx];
        const int j   = (int)(ent >> 2);
        const int row = (int)(ent & 3u) * 64 + lane;

        const float bv  = bmap[j];
        const float qv  = qini[j];
        const float ev  = eps[j];
        const float obv = 1.0f - bv;
        const float rb  = 1.0f / bv;
        const float rob = 1.0f / obv;

        const float xv  = x[(size_t)row * NN + j];
        const float lov = xv - ev;
        const float hiv = xv + ev;

        float m = qv, anchor = qv;
        int   window = 1, steps = 0;
        int   kk = 1;
        bool  a  = (qv != 0.0f);
        bool  cycseen = false;

        int it = 0;
        while (it < MAX_ITERS) {
            #pragma unroll
            for (int u = 0; u < 4; ++u) {
                const bool  lt = (m < bv);
                const float pa = m * rb;
                const float pb = (1.0f - m) * rob;
                m = lt ? pa : pb;
                cycseen = cycseen || (m == anchor);
                if (++steps == window) { anchor = m; window <<= 1; steps = 0; }
                const bool o = (m < lov) || (m > hiv);
                a = a && o;
                kk += a ? 1 : 0;
            }
            it += 4;
            if (__ballot(a) == 0ull) break;
            if (cycseen) { kk += a ? (MAX_ITERS - it) : 0; break; }
        }

        kout[(size_t)row * NN + j] = (float)kk;
    }
}

// ---------------------------------------------------------------------------
// M-norm kernel: 100 blocks, f64 sumsq in the r14-proven order
// (threadIdx*4, stride-1024 float4). Mn[c] = max(sqrt, 1e-8).
// ---------------------------------------------------------------------------
__global__ __launch_bounds__(256) void normM_kernel(
    const float* __restrict__ M, float* __restrict__ Mn)
{
    __shared__ double red[4];
    const float* src = M + (size_t)blockIdx.x * NN;
    double s = 0.0;
    for (int j = threadIdx.x * 4; j < NN; j += 1024) {
        const float4 v = *(const float4*)(src + j);
        s += (double)v.x * v.x + (double)v.y * v.y
           + (double)v.z * v.z + (double)v.w * v.w;
    }
    #pragma unroll
    for (int off = 32; off; off >>= 1) s += __shfl_down(s, off, 64);
    const int wid = threadIdx.x >> 6, lane = threadIdx.x & 63;
    if (lane == 0) red[wid] = s;
    __syncthreads();
    if (threadIdx.x == 0)
        Mn[blockIdx.x] = fmaxf((float)sqrt(red[0] + red[1] + red[2] + red[3]), 1e-8f);
}

// ---------------------------------------------------------------------------
// Logits kernel (r15 minus inline M-norms): block = (row-quad, 10-class
// chunk), grid 640. k-norm phase and dot order identical to r15 (proven).
// ---------------------------------------------------------------------------
__global__ __launch_bounds__(256) void logits_kernel(
    const float* __restrict__ k, const float* __restrict__ M,
    const float* __restrict__ Mn, float* __restrict__ out)
{
    __shared__ float  redd[4][4];
    __shared__ double redk[4][4];
    __shared__ float  knsh[4];

    const int rq  = blockIdx.x / CHUNK;
    const int ch  = blockIdx.x % CHUNK;
    const int i0  = rq * 4;
    const int tid = threadIdx.x;
    const int wid = tid >> 6, lane = tid & 63;

    float4 kr[4][8];
    #pragma unroll
    for (int r = 0; r < 4; ++r)
        #pragma unroll
        for (int s = 0; s < 8; ++s)
            kr[r][s] = *(const float4*)(k + (size_t)(i0 + r) * NN + s * 1024 + tid * 4);

    {   // k-row norms (f64), r15-identical order
        double ks[4] = {0.0, 0.0, 0.0, 0.0};
        #pragma unroll
        for (int s = 0; s < 8; ++s)
            #pragma unroll
            for (int r = 0; r < 4; ++r) {
                const float4 v = kr[r][s];
                ks[r] += (double)v.x * v.x + (double)v.y * v.y
                       + (double)v.z * v.z + (double)v.w * v.w;
            }
        #pragma unroll
        for (int off = 32; off; off >>= 1)
            #pragma unroll
            for (int r = 0; r < 4; ++r) ks[r] += __shfl_down(ks[r], off, 64);
        if (lane == 0)
            #pragma unroll
            for (int r = 0; r < 4; ++r) redk[wid][r] = ks[r];
        __syncthreads();
        if (tid < 4) {
            const double t = redk[0][tid] + redk[1][tid] + redk[2][tid] + redk[3][tid];
            knsh[tid] = fmaxf((float)sqrt(t), 1e-8f);
        }
        __syncthreads();
    }

    for (int c = ch * CHUNK; c < ch * CHUNK + CHUNK; ++c) {
        const float4* Mp = (const float4*)(M + (size_t)c * NN);
        float acc[4] = {0.0f, 0.0f, 0.0f, 0.0f};
        #pragma unroll
        for (int s = 0; s < 8; ++s) {
            const float4 mv = Mp[s * 256 + tid];
            #pragma unroll
            for (int r = 0; r < 4; ++r)
                acc[r] += kr[r][s].x * mv.x + kr[r][s].y * mv.y
                        + kr[r][s].z * mv.z + kr[r][s].w * mv.w;
        }
        #pragma unroll
        for (int off = 32; off; off >>= 1)
            #pragma unroll
            for (int r = 0; r < 4; ++r) acc[r] += __shfl_down(acc[r], off, 64);
        if (lane == 0)
            #pragma unroll
            for (int r = 0; r < 4; ++r) redd[wid][r] = acc[r];
        __syncthreads();
        if (tid < 4) {
            const float d = redd[0][tid] + redd[1][tid] + redd[2][tid] + redd[3][tid];
            out[(size_t)(i0 + tid) * CC + c] = d / (knsh[tid] * Mn[c]);
        }
        __syncthreads();
    }
}

// ===========================================================================
// FALLBACK: round-10 fused kernel, verbatim (proven green), used only if
// ws_size is too small.
// ===========================================================================
__global__ __launch_bounds__(256) void gls_fused_kernel(
    const float* __restrict__ x, const float* __restrict__ bmap,
    const float* __restrict__ qini, const float* __restrict__ eps,
    const float* __restrict__ M, float* __restrict__ out)
{
    __shared__ float k_lds[NN];
    __shared__ double redsh[4];

    const int i   = blockIdx.x;
    const int tid = threadIdx.x;
    const int wid = tid >> 6, lane = tid & 63;

    double sumsq = 0.0;
    for (int s = 0; s < 32; ++s) {
        const int j = tid + 256 * s;
        const float bv = bmap[j];
        const float qv = qini[j];
        const float ev = eps[j];
        const float xv = x[(size_t)i * NN + j];
        const float lov = xv - ev;
        const float hiv = xv + ev;
        const float obv = 1.0f - bv;
        const float rb  = 1.0f / bv;
        const float rob = 1.0f / obv;

        float m  = qv;
        float kk = 1.0f;
        bool  a  = (qv != 0.0f);
        for (int it = 0; a && it < MAX_ITERS; ++it) {
            const bool  lt  = (m < bv);
            const float num = lt ? m  : (1.0f - m);
            const float r   = lt ? rb : rob;
            m = num * r;
            a = (m < lov) || (m > hiv);
            kk += a ? 1.0f : 0.0f;
        }
        k_lds[j] = kk;
        sumsq += (double)kk * (double)kk;
    }

    #pragma unroll
    for (int off = 32; off; off >>= 1) sumsq += __shfl_down(sumsq, off, 64);
    if (lane == 0) redsh[wid] = sumsq;
    __syncthreads();
    const double rn = fmax(sqrt(redsh[0] + redsh[1] + redsh[2] + redsh[3]), 1e-8);

    for (int cc2 = 0; cc2 < 25; ++cc2) {
        const int c = wid * 25 + cc2;
        const float4* Mp = (const float4*)(M + (size_t)c * NN);
        double dot = 0.0, msq = 0.0;
        #pragma unroll 4
        for (int s = 0; s < 32; ++s) {
            const float4 mv = Mp[lane + 64 * s];
            const float4 kv = *(const float4*)(&k_lds[4 * (lane + 64 * s)]);
            dot += (double)kv.x * (double)mv.x + (double)kv.y * (double)mv.y
                 + (double)kv.z * (double)mv.z + (double)kv.w * (double)mv.w;
            msq += (double)mv.x * (double)mv.x + (double)mv.y * (double)mv.y
                 + (double)mv.z * (double)mv.z + (double)mv.w * (double)mv.w;
        }
        #pragma unroll
        for (int off = 32; off; off >>= 1) {
            dot += __shfl_down(dot, off, 64);
            msq += __shfl_down(msq, off, 64);
        }
        if (lane == 0) {
            const double mn = fmax(sqrt(msq), 1e-8);
            out[(size_t)i * CC + c] = (float)(dot / (rn * mn));
        }
    }
}

// ---------------------------------------------------------------------------
extern "C" void kernel_launch(void* const* d_in, const int* in_sizes, int n_in,
                              void* d_out, int out_size, void* d_ws, size_t ws_size,
                              hipStream_t stream) {
    const float* x = (const float*)d_in[0];  // (256, 8192)
    const float* b = (const float*)d_in[1];  // (8192,)
    const float* q = (const float*)d_in[2];  // (8192,)
    const float* e = (const float*)d_in[3];  // (8192,)
    const float* M = (const float*)d_in[4];  // (100, 8192)
    float* out = (float*)d_out;              // (256, 100)

    // ws layout: kbuf | Mn[100] | cnt (u32) | list[LISTMAX] (u32)
    const size_t kbytes    = (size_t)BB * NN * sizeof(float);
    const size_t need_full = kbytes + CC * sizeof(float) + 64
                           + sizeof(unsigned) * (LISTMAX + 1);

    if (ws_size >= need_full) {
        float*    kbuf = (float*)d_ws;
        float*    Mn   = kbuf + (size_t)BB * NN;
        unsigned* cnt  = (unsigned*)((char*)d_ws + kbytes + CC * sizeof(float));
        unsigned* list = cnt + 1;

        zero_kernel<<<dim3(1), dim3(1), 0, stream>>>(cnt);
        fireA_kernel<<<dim3(NN), dim3(256), 0, stream>>>(x, b, q, e, kbuf, cnt, list);
        fireB_kernel<<<dim3(512), dim3(64), 0, stream>>>(x, b, q, e, kbuf, cnt, list);
        normM_kernel<<<dim3(CC), dim3(256), 0, stream>>>(M, Mn);
        logits_kernel<<<dim3((BB / 4) * CHUNK), dim3(256), 0, stream>>>(kbuf, M, Mn, out);
    } else {
        gls_fused_kernel<<<dim3(BB), dim3(256), 0, stream>>>(x, b, q, e, M, out);
    }
}

// Round 17
// 117.934 us; speedup vs baseline: 1.3442x; 1.3442x over previous
//
#include <hip/hip_runtime.h>
#include <math.h>

// Problem constants: x(256,8192) b,q,e(8192) M(100,8192) out(256,100)
#define NN 8192
#define BB 256
#define CC 100
#define MAX_ITERS 4096
#define CHUNK 10   // classes per logits block

// ---------------------------------------------------------------------------
// Fire kernel (r15 verbatim, measured 81 us): wave = one column x 64 rows.
// Map trajectory is wave-uniform; per-lane band checks; unroll-4 window with
// deferred exits (ballot + cycle branch once per 4 iters; post-fire wasted
// iters harmless since a is already false).
// Cycle fast-forward (bit-exact): when the uniform trajectory repeats a
// previously-survived value, still-active lanes can never fire ->
// kk += MAX_ITERS - it. Locked reference flavor (r10): hoisted IEEE f32
// reciprocals rb=1.0f/b, rob=1.0f/(1-b); m' = (m<b ? m*rb : (1-m)*rob);
// separate sub/mul/select (no FMA contraction); lo=x-e, hi=x+e exact subs.
// ---------------------------------------------------------------------------
__global__ __launch_bounds__(256) void fire_kernel(
    const float* __restrict__ x, const float* __restrict__ bmap,
    const float* __restrict__ qini, const float* __restrict__ eps,
    float* __restrict__ kout)
{
    const int j    = blockIdx.x;              // column (one per block)
    const int lane = threadIdx.x & 63;
    const int row  = (threadIdx.x & ~63) + lane;   // wave w covers rows 64w..64w+63

    const float bv  = bmap[j];                // uniform across the wave
    const float qv  = qini[j];
    const float ev  = eps[j];
    const float obv = 1.0f - bv;              // exact (Sterbenz)
    const float rb  = 1.0f / bv;              // hoisted IEEE f32 reciprocals
    const float rob = 1.0f / obv;

    const float xv  = x[(size_t)row * NN + j];     // scattered dword load (once)
    const float lov = xv - ev;                // exact f32 subs, same bits as ref
    const float hiv = xv + ev;

    float m = qv, anchor = qv;                // uniform trajectory state
    int   window = 1, steps = 0;
    int   kk = 1;
    bool  a  = (qv != 0.0f);                  // q==0: never fires
    bool  cycseen = false;

    int it = 0;
    while (it < MAX_ITERS) {
        #pragma unroll
        for (int u = 0; u < 4; ++u) {
            const bool  lt = (m < bv);
            const float pa = m * rb;
            const float pb = (1.0f - m) * rob;
            m = lt ? pa : pb;

            cycseen = cycseen || (m == anchor);   // Brent probe
            if (++steps == window) { anchor = m; window <<= 1; steps = 0; }

            const bool o = (m < lov) || (m > hiv);
            a = a && o;
            kk += a ? 1 : 0;
        }
        it += 4;
        if (__ballot(a) == 0ull) break;       // all 64 rows fired
        if (cycseen) {                        // trajectory periodic ->
            kk += a ? (MAX_ITERS - it) : 0;   // survivors never fire (exact)
            break;
        }
    }

    kout[(size_t)row * NN + j] = (float)kk;   // scattered dword store (once)
}

// ---------------------------------------------------------------------------
// M-norm kernel (r16 verbatim): 100 blocks, f64 sumsq in the r14-proven
// order (threadIdx*4, stride-1024 float4). Mn[c] = max(sqrt, 1e-8).
// ---------------------------------------------------------------------------
__global__ __launch_bounds__(256) void normM_kernel(
    const float* __restrict__ M, float* __restrict__ Mn)
{
    __shared__ double red[4];
    const float* src = M + (size_t)blockIdx.x * NN;
    double s = 0.0;
    for (int j = threadIdx.x * 4; j < NN; j += 1024) {
        const float4 v = *(const float4*)(src + j);
        s += (double)v.x * v.x + (double)v.y * v.y
           + (double)v.z * v.z + (double)v.w * v.w;
    }
    #pragma unroll
    for (int off = 32; off; off >>= 1) s += __shfl_down(s, off, 64);
    const int wid = threadIdx.x >> 6, lane = threadIdx.x & 63;
    if (lane == 0) red[wid] = s;
    __syncthreads();
    if (threadIdx.x == 0)
        Mn[blockIdx.x] = fmaxf((float)sqrt(red[0] + red[1] + red[2] + red[3]), 1e-8f);
}

// ---------------------------------------------------------------------------
// Logits kernel (r16 verbatim): block = (row-quad, 10-class chunk), grid 640.
// k rows in registers; k-row norms from those registers (f64, proven order);
// dot order identical to the r12/r14/r15 proven pipeline.
// ---------------------------------------------------------------------------
__global__ __launch_bounds__(256) void logits_kernel(
    const float* __restrict__ k, const float* __restrict__ M,
    const float* __restrict__ Mn, float* __restrict__ out)
{
    __shared__ float  redd[4][4];
    __shared__ double redk[4][4];
    __shared__ float  knsh[4];

    const int rq  = blockIdx.x / CHUNK;
    const int ch  = blockIdx.x % CHUNK;
    const int i0  = rq * 4;
    const int tid = threadIdx.x;
    const int wid = tid >> 6, lane = tid & 63;

    float4 kr[4][8];
    #pragma unroll
    for (int r = 0; r < 4; ++r)
        #pragma unroll
        for (int s = 0; s < 8; ++s)
            kr[r][s] = *(const float4*)(k + (size_t)(i0 + r) * NN + s * 1024 + tid * 4);

    {   // k-row norms (f64), proven order
        double ks[4] = {0.0, 0.0, 0.0, 0.0};
        #pragma unroll
        for (int s = 0; s < 8; ++s)
            #pragma unroll
            for (int r = 0; r < 4; ++r) {
                const float4 v = kr[r][s];
                ks[r] += (double)v.x * v.x + (double)v.y * v.y
                       + (double)v.z * v.z + (double)v.w * v.w;
            }
        #pragma unroll
        for (int off = 32; off; off >>= 1)
            #pragma unroll
            for (int r = 0; r < 4; ++r) ks[r] += __shfl_down(ks[r], off, 64);
        if (lane == 0)
            #pragma unroll
            for (int r = 0; r < 4; ++r) redk[wid][r] = ks[r];
        __syncthreads();
        if (tid < 4) {
            const double t = redk[0][tid] + redk[1][tid] + redk[2][tid] + redk[3][tid];
            knsh[tid] = fmaxf((float)sqrt(t), 1e-8f);
        }
        __syncthreads();
    }

    for (int c = ch * CHUNK; c < ch * CHUNK + CHUNK; ++c) {
        const float4* Mp = (const float4*)(M + (size_t)c * NN);
        float acc[4] = {0.0f, 0.0f, 0.0f, 0.0f};
        #pragma unroll
        for (int s = 0; s < 8; ++s) {
            const float4 mv = Mp[s * 256 + tid];
            #pragma unroll
            for (int r = 0; r < 4; ++r)
                acc[r] += kr[r][s].x * mv.x + kr[r][s].y * mv.y
                        + kr[r][s].z * mv.z + kr[r][s].w * mv.w;
        }
        #pragma unroll
        for (int off = 32; off; off >>= 1)
            #pragma unroll
            for (int r = 0; r < 4; ++r) acc[r] += __shfl_down(acc[r], off, 64);
        if (lane == 0)
            #pragma unroll
            for (int r = 0; r < 4; ++r) redd[wid][r] = acc[r];
        __syncthreads();
        if (tid < 4) {
            const float d = redd[0][tid] + redd[1][tid] + redd[2][tid] + redd[3][tid];
            out[(size_t)(i0 + tid) * CC + c] = d / (knsh[tid] * Mn[c]);
        }
        __syncthreads();
    }
}

// ===========================================================================
// FALLBACK: round-10 fused kernel, verbatim (proven green), used only if
// ws_size is too small.
// ===========================================================================
__global__ __launch_bounds__(256) void gls_fused_kernel(
    const float* __restrict__ x, const float* __restrict__ bmap,
    const float* __restrict__ qini, const float* __restrict__ eps,
    const float* __restrict__ M, float* __restrict__ out)
{
    __shared__ float k_lds[NN];
    __shared__ double redsh[4];

    const int i   = blockIdx.x;
    const int tid = threadIdx.x;
    const int wid = tid >> 6, lane = tid & 63;

    double sumsq = 0.0;
    for (int s = 0; s < 32; ++s) {
        const int j = tid + 256 * s;
        const float bv = bmap[j];
        const float qv = qini[j];
        const float ev = eps[j];
        const float xv = x[(size_t)i * NN + j];
        const float lov = xv - ev;
        const float hiv = xv + ev;
        const float obv = 1.0f - bv;
        const float rb  = 1.0f / bv;
        const float rob = 1.0f / obv;

        float m  = qv;
        float kk = 1.0f;
        bool  a  = (qv != 0.0f);
        for (int it = 0; a && it < MAX_ITERS; ++it) {
            const bool  lt  = (m < bv);
            const float num = lt ? m  : (1.0f - m);
            const float r   = lt ? rb : rob;
            m = num * r;
            a = (m < lov) || (m > hiv);
            kk += a ? 1.0f : 0.0f;
        }
        k_lds[j] = kk;
        sumsq += (double)kk * (double)kk;
    }

    #pragma unroll
    for (int off = 32; off; off >>= 1) sumsq += __shfl_down(sumsq, off, 64);
    if (lane == 0) redsh[wid] = sumsq;
    __syncthreads();
    const double rn = fmax(sqrt(redsh[0] + redsh[1] + redsh[2] + redsh[3]), 1e-8);

    for (int cc2 = 0; cc2 < 25; ++cc2) {
        const int c = wid * 25 + cc2;
        const float4* Mp = (const float4*)(M + (size_t)c * NN);
        double dot = 0.0, msq = 0.0;
        #pragma unroll 4
        for (int s = 0; s < 32; ++s) {
            const float4 mv = Mp[lane + 64 * s];
            const float4 kv = *(const float4*)(&k_lds[4 * (lane + 64 * s)]);
            dot += (double)kv.x * (double)mv.x + (double)kv.y * (double)mv.y
                 + (double)kv.z * (double)mv.z + (double)kv.w * (double)mv.w;
            msq += (double)mv.x * (double)mv.x + (double)mv.y * (double)mv.y
                 + (double)mv.z * (double)mv.z + (double)mv.w * (double)mv.w;
        }
        #pragma unroll
        for (int off = 32; off; off >>= 1) {
            dot += __shfl_down(dot, off, 64);
            msq += __shfl_down(msq, off, 64);
        }
        if (lane == 0) {
            const double mn = fmax(sqrt(msq), 1e-8);
            out[(size_t)i * CC + c] = (float)(dot / (rn * mn));
        }
    }
}

// ---------------------------------------------------------------------------
extern "C" void kernel_launch(void* const* d_in, const int* in_sizes, int n_in,
                              void* d_out, int out_size, void* d_ws, size_t ws_size,
                              hipStream_t stream) {
    const float* x = (const float*)d_in[0];  // (256, 8192)
    const float* b = (const float*)d_in[1];  // (8192,)
    const float* q = (const float*)d_in[2];  // (8192,)
    const float* e = (const float*)d_in[3];  // (8192,)
    const float* M = (const float*)d_in[4];  // (100, 8192)
    float* out = (float*)d_out;              // (256, 100)

    // ws layout: kbuf | Mn[100]
    const size_t need = (size_t)BB * NN * sizeof(float) + CC * sizeof(float);
    if (ws_size >= need) {
        float* kbuf = (float*)d_ws;
        float* Mn   = kbuf + (size_t)BB * NN;
        fire_kernel<<<dim3(NN), dim3(256), 0, stream>>>(x, b, q, e, kbuf);
        normM_kernel<<<dim3(CC), dim3(256), 0, stream>>>(M, Mn);
        logits_kernel<<<dim3((BB / 4) * CHUNK), dim3(256), 0, stream>>>(kbuf, M, Mn, out);
    } else {
        gls_fused_kernel<<<dim3(BB), dim3(256), 0, stream>>>(x, b, q, e, M, out);
    }
}

// Round 18
// 106.056 us; speedup vs baseline: 1.4948x; 1.1120x over previous
//
#include <hip/hip_runtime.h>
#include <math.h>

// Problem constants: x(256,8192) b,q,e(8192) M(100,8192) out(256,100)
#define NN 8192
#define BB 256
#define CC 100
#define MAX_ITERS 4096

// ---------------------------------------------------------------------------
// Fire kernel (r15/r17 verbatim, measured 81-83 us): wave = one column x 64
// rows. Wave-uniform map trajectory; per-lane band checks; unroll-4 window
// with deferred exits. Brent cycle fast-forward (bit-exact). Locked
// reference flavor (r10): hoisted IEEE f32 reciprocals rb=1.0f/b,
// rob=1.0f/(1-b); m' = (m<b ? m*rb : (1-m)*rob); lo=x-e, hi=x+e exact subs.
// ---------------------------------------------------------------------------
__global__ __launch_bounds__(256) void fire_kernel(
    const float* __restrict__ x, const float* __restrict__ bmap,
    const float* __restrict__ qini, const float* __restrict__ eps,
    float* __restrict__ kout)
{
    const int j    = blockIdx.x;              // column (one per block)
    const int lane = threadIdx.x & 63;
    const int row  = (threadIdx.x & ~63) + lane;   // wave w covers rows 64w..64w+63

    const float bv  = bmap[j];                // uniform across the wave
    const float qv  = qini[j];
    const float ev  = eps[j];
    const float obv = 1.0f - bv;              // exact (Sterbenz)
    const float rb  = 1.0f / bv;              // hoisted IEEE f32 reciprocals
    const float rob = 1.0f / obv;

    const float xv  = x[(size_t)row * NN + j];     // scattered dword load (once)
    const float lov = xv - ev;                // exact f32 subs, same bits as ref
    const float hiv = xv + ev;

    float m = qv, anchor = qv;                // uniform trajectory state
    int   window = 1, steps = 0;
    int   kk = 1;
    bool  a  = (qv != 0.0f);                  // q==0: never fires
    bool  cycseen = false;

    int it = 0;
    while (it < MAX_ITERS) {
        #pragma unroll
        for (int u = 0; u < 4; ++u) {
            const bool  lt = (m < bv);
            const float pa = m * rb;
            const float pb = (1.0f - m) * rob;
            m = lt ? pa : pb;

            cycseen = cycseen || (m == anchor);   // Brent probe
            if (++steps == window) { anchor = m; window <<= 1; steps = 0; }

            const bool o = (m < lov) || (m > hiv);
            a = a && o;
            kk += a ? 1 : 0;
        }
        it += 4;
        if (__ballot(a) == 0ull) break;       // all 64 rows fired
        if (cycseen) {                        // trajectory periodic ->
            kk += a ? (MAX_ITERS - it) : 0;   // survivors never fire (exact)
            break;
        }
    }

    kout[(size_t)row * NN + j] = (float)kk;   // scattered dword store (once)
}

// ---------------------------------------------------------------------------
// Norm kernel (r14 verbatim, proven): blocks 0..255 -> ||k[i]||,
// 256..355 -> ||M[c]||. f64 accumulation; norms[row] = max(sqrt, 1e-8).
// ---------------------------------------------------------------------------
__global__ __launch_bounds__(256) void norm_kernel(
    const float* __restrict__ k, const float* __restrict__ M,
    float* __restrict__ norms)
{
    __shared__ double red[4];
    const int row = blockIdx.x;
    const float* src = (row < BB) ? (k + (size_t)row * NN)
                                  : (M + (size_t)(row - BB) * NN);
    double s = 0.0;
    for (int j = threadIdx.x * 4; j < NN; j += 1024) {
        const float4 v = *(const float4*)(src + j);
        s += (double)v.x * v.x + (double)v.y * v.y
           + (double)v.z * v.z + (double)v.w * v.w;
    }
    #pragma unroll
    for (int off = 32; off; off >>= 1) s += __shfl_down(s, off, 64);
    const int wid = threadIdx.x >> 6, lane = threadIdx.x & 63;
    if (lane == 0) red[wid] = s;
    __syncthreads();
    if (threadIdx.x == 0)
        norms[row] = fmaxf((float)sqrt(red[0] + red[1] + red[2] + red[3]), 1e-8f);
}

// ---------------------------------------------------------------------------
// Logits GEMM kernel: block = (8-row tile x 5-class tile), grid 32x20=640.
// Per-thread 40 f32 accumulators; j-loop of 8 coalesced float4 steps; ONE
// shuffle-ladder reduction + ONE barrier at the end (vs 10 ladders / 20
// barriers in the per-class structure). out = dot / (kn * Mn).
// ---------------------------------------------------------------------------
#define TR 8
#define TC 5
__global__ __launch_bounds__(256) void logits_gemm(
    const float* __restrict__ k, const float* __restrict__ M,
    const float* __restrict__ norms, float* __restrict__ out)
{
    __shared__ float red[4][TR][TC];

    const int rt  = blockIdx.x / (CC / TC);   // 0..31 row tile
    const int ct  = blockIdx.x % (CC / TC);   // 0..19 class tile
    const int r0  = rt * TR, c0 = ct * TC;
    const int tid = threadIdx.x;
    const int wid = tid >> 6, lane = tid & 63;

    float acc[TR][TC];
    #pragma unroll
    for (int r = 0; r < TR; ++r)
        #pragma unroll
        for (int c = 0; c < TC; ++c) acc[r][c] = 0.0f;

    for (int s = 0; s < 8; ++s) {
        const int jj = s * 1024 + tid * 4;
        float4 mv[TC];
        #pragma unroll
        for (int c = 0; c < TC; ++c)
            mv[c] = *(const float4*)(M + (size_t)(c0 + c) * NN + jj);
        #pragma unroll
        for (int r = 0; r < TR; ++r) {
            const float4 kv = *(const float4*)(k + (size_t)(r0 + r) * NN + jj);
            #pragma unroll
            for (int c = 0; c < TC; ++c)
                acc[r][c] += kv.x * mv[c].x + kv.y * mv[c].y
                           + kv.z * mv[c].z + kv.w * mv[c].w;
        }
    }

    // wave-level ladder for all 40 outputs, then one LDS combine
    #pragma unroll
    for (int off = 32; off; off >>= 1)
        #pragma unroll
        for (int r = 0; r < TR; ++r)
            #pragma unroll
            for (int c = 0; c < TC; ++c)
                acc[r][c] += __shfl_down(acc[r][c], off, 64);
    if (lane == 0)
        #pragma unroll
        for (int r = 0; r < TR; ++r)
            #pragma unroll
            for (int c = 0; c < TC; ++c)
                red[wid][r][c] = acc[r][c];
    __syncthreads();

    if (tid < TR * TC) {
        const int r = tid / TC, c = tid % TC;
        const float d = red[0][r][c] + red[1][r][c] + red[2][r][c] + red[3][r][c];
        out[(size_t)(r0 + r) * CC + (c0 + c)] =
            d / (norms[r0 + r] * norms[BB + c0 + c]);
    }
}

// ===========================================================================
// FALLBACK: round-10 fused kernel, verbatim (proven green), used only if
// ws_size is too small.
// ===========================================================================
__global__ __launch_bounds__(256) void gls_fused_kernel(
    const float* __restrict__ x, const float* __restrict__ bmap,
    const float* __restrict__ qini, const float* __restrict__ eps,
    const float* __restrict__ M, float* __restrict__ out)
{
    __shared__ float k_lds[NN];
    __shared__ double redsh[4];

    const int i   = blockIdx.x;
    const int tid = threadIdx.x;
    const int wid = tid >> 6, lane = tid & 63;

    double sumsq = 0.0;
    for (int s = 0; s < 32; ++s) {
        const int j = tid + 256 * s;
        const float bv = bmap[j];
        const float qv = qini[j];
        const float ev = eps[j];
        const float xv = x[(size_t)i * NN + j];
        const float lov = xv - ev;
        const float hiv = xv + ev;
        const float obv = 1.0f - bv;
        const float rb  = 1.0f / bv;
        const float rob = 1.0f / obv;

        float m  = qv;
        float kk = 1.0f;
        bool  a  = (qv != 0.0f);
        for (int it = 0; a && it < MAX_ITERS; ++it) {
            const bool  lt  = (m < bv);
            const float num = lt ? m  : (1.0f - m);
            const float r   = lt ? rb : rob;
            m = num * r;
            a = (m < lov) || (m > hiv);
            kk += a ? 1.0f : 0.0f;
        }
        k_lds[j] = kk;
        sumsq += (double)kk * (double)kk;
    }

    #pragma unroll
    for (int off = 32; off; off >>= 1) sumsq += __shfl_down(sumsq, off, 64);
    if (lane == 0) redsh[wid] = sumsq;
    __syncthreads();
    const double rn = fmax(sqrt(redsh[0] + redsh[1] + redsh[2] + redsh[3]), 1e-8);

    for (int cc2 = 0; cc2 < 25; ++cc2) {
        const int c = wid * 25 + cc2;
        const float4* Mp = (const float4*)(M + (size_t)c * NN);
        double dot = 0.0, msq = 0.0;
        #pragma unroll 4
        for (int s = 0; s < 32; ++s) {
            const float4 mv = Mp[lane + 64 * s];
            const float4 kv = *(const float4*)(&k_lds[4 * (lane + 64 * s)]);
            dot += (double)kv.x * (double)mv.x + (double)kv.y * (double)mv.y
                 + (double)kv.z * (double)mv.z + (double)kv.w * (double)mv.w;
            msq += (double)mv.x * (double)mv.x + (double)mv.y * (double)mv.y
                 + (double)mv.z * (double)mv.z + (double)mv.w * (double)mv.w;
        }
        #pragma unroll
        for (int off = 32; off; off >>= 1) {
            dot += __shfl_down(dot, off, 64);
            msq += __shfl_down(msq, off, 64);
        }
        if (lane == 0) {
            const double mn = fmax(sqrt(msq), 1e-8);
            out[(size_t)i * CC + c] = (float)(dot / (rn * mn));
        }
    }
}

// ---------------------------------------------------------------------------
extern "C" void kernel_launch(void* const* d_in, const int* in_sizes, int n_in,
                              void* d_out, int out_size, void* d_ws, size_t ws_size,
                              hipStream_t stream) {
    const float* x = (const float*)d_in[0];  // (256, 8192)
    const float* b = (const float*)d_in[1];  // (8192,)
    const float* q = (const float*)d_in[2];  // (8192,)
    const float* e = (const float*)d_in[3];  // (8192,)
    const float* M = (const float*)d_in[4];  // (100, 8192)
    float* out = (float*)d_out;              // (256, 100)

    // ws layout: kbuf | norms[356]
    const size_t need = (size_t)BB * NN * sizeof(float) + (BB + CC) * sizeof(float);
    if (ws_size >= need) {
        float* kbuf  = (float*)d_ws;
        float* norms = kbuf + (size_t)BB * NN;
        fire_kernel<<<dim3(NN), dim3(256), 0, stream>>>(x, b, q, e, kbuf);
        norm_kernel<<<dim3(BB + CC), dim3(256), 0, stream>>>(kbuf, M, norms);
        logits_gemm<<<dim3((BB / TR) * (CC / TC)), dim3(256), 0, stream>>>(kbuf, M, norms, out);
    } else {
        gls_fused_kernel<<<dim3(BB), dim3(256), 0, stream>>>(x, b, q, e, M, out);
    }
}